// Round 6
// baseline (746.350 us; speedup 1.0000x reference)
//
#include <hip/hip_runtime.h>
#include <cstdint>

// Problem constants (fixed by reference):
#define Bc 1024
#define Tc 4096
#define Nc 2048
#define Kc 16
#define Mc 65536

#define Gn 8               // memory rows per block in probe kernel
#define GRID_B (Nc / Gn)   // 256 blocks

#define PACK_GRID 2048
#define PACK_BLK  256

// clang ext_vector types (HIP_vector_type int4 is NOT accepted by
// __builtin_nontemporal_load/store).
typedef int  v4i  __attribute__((ext_vector_type(4)));
typedef uint v4u  __attribute__((ext_vector_type(4)));

// ---------------------------------------------------------------------------
// Kernel P: pack bit0 of memory[N][M] into a 16 MB bitset in workspace.
// VERBATIM from round 1 (end-to-end verified, and the only structure measured
// to stream the 512 MB at near-roofline: grid-strided => globally
// quasi-sequential HBM pattern, unlike per-block private 2MB streams which
// measured ~3x slower in rounds 4/5).
// Layout: packed64[e >> 6] bit (e & 63) = bit0 of element e, e = n*Mc + m.
// ---------------------------------------------------------------------------
__global__ __launch_bounds__(PACK_BLK) void pack_bit0(
    const int* __restrict__ memory,
    unsigned long long* __restrict__ packed)   // Nc*Mc/64 u64 = 16 MB
{
    const int tid  = threadIdx.x;
    const int lane = tid & 63;
    const size_t stride = (size_t)PACK_GRID * PACK_BLK;   // 524288
    size_t base = (size_t)blockIdx.x * PACK_BLK + tid;

    for (int it = 0; it < 256 / 8; ++it) {                // 32 outer iters
        int v[8];
#pragma unroll
        for (int j = 0; j < 8; ++j)                        // 8 loads in flight
            v[j] = __builtin_nontemporal_load(memory + base + (size_t)j * stride);
#pragma unroll
        for (int j = 0; j < 8; ++j) {
            const unsigned long long m = __ballot(v[j] & 1);
            if (lane == 0) {
                // lane0's elem index is 64-aligned (blockDim=256, stride%64==0)
                packed[(base + (size_t)j * stride) >> 6] = m;
            }
        }
        base += 8 * stride;
    }
}

// ---------------------------------------------------------------------------
// Kernel A (b-major): compute all 16-bit addresses, store u16 to workspace.
// Verified in round 4 (absmax 0). Unchanged.
// ---------------------------------------------------------------------------
__global__ __launch_bounds__(256) void addr_kernel(
    const int* __restrict__ input_bits,     // (B, T)
    const int* __restrict__ connections,    // (N, K)
    unsigned short* __restrict__ addr)      // (B, N) u16
{
    __shared__ uint32_t bits[Tc / 32];      // 512 B

    const int b    = blockIdx.x;
    const int tid  = threadIdx.x;
    const int lane = tid & 63;
    const int wave = tid >> 6;

    const int* row = input_bits + (size_t)b * Tc;

#pragma unroll
    for (int i = 0; i < Tc / 256; ++i) {    // 16 iterations
        const int pos = i * 256 + wave * 64 + lane;
        const unsigned long long m = __ballot(row[pos] & 1);
        if (lane == 0) {
            const int w64 = i * 4 + wave;
            bits[w64 * 2]     = (uint32_t)m;
            bits[w64 * 2 + 1] = (uint32_t)(m >> 32);
        }
    }
    __syncthreads();

#pragma unroll
    for (int i = 0; i < Nc / 256; ++i) {    // 8 iterations
        const int n = i * 256 + tid;
        const int4* cp = (const int4*)(connections + n * Kc);
        const int4 c0 = cp[0], c1 = cp[1], c2 = cp[2], c3 = cp[3];
        const int c[16] = {c0.x, c0.y, c0.z, c0.w,
                           c1.x, c1.y, c1.z, c1.w,
                           c2.x, c2.y, c2.z, c2.w,
                           c3.x, c3.y, c3.z, c3.w};
        uint32_t a = 0;
#pragma unroll
        for (int k = 0; k < 16; ++k) {
            const uint32_t t = (uint32_t)c[k];
            a |= ((bits[t >> 5] >> (t & 31)) & 1u) << k;
        }
        addr[(size_t)b * Nc + n] = (unsigned short)a;   // coalesced 128B/wave
    }
}

// ---------------------------------------------------------------------------
// Kernel B: each block copies its 8 PACKED rows (64 KB, fully contiguous in
// the packed table) into LDS, then probes for all 1024 batches.
// Probe: row p = n - n0, word = prow[p*2048 + (a>>5)], bit = a & 31.
// ---------------------------------------------------------------------------
__global__ __launch_bounds__(256) void probe_kernel(
    const uint32_t* __restrict__ packed32,   // Nc * 2048 u32 (16 MB)
    const unsigned short* __restrict__ addr, // (B, N)
    int* __restrict__ out)                   // (B, N) bool-as-int32
{
    __shared__ uint32_t prow[Gn * 2048];     // 64 KB

    const int n0  = blockIdx.x * Gn;
    const int tid = threadIdx.x;

    // ---- Phase 1: contiguous 64 KB global -> LDS copy ----
    const v4u* src = (const v4u*)(packed32 + (size_t)n0 * 2048);
#pragma unroll
    for (int i = 0; i < 16; ++i) {           // 16384 words / (256 thr * 4)
        const int w = i * 256 + tid;         // v4u index
        const v4u x = src[w];
        *(v4u*)&prow[w * 4] = x;
    }
    __syncthreads();

    // ---- Phase 2: probe LDS for all 1024 b's, 8 n's per thread-iter ----
    // Hoist all 4 divergent addr loads up front for MLP.
    v4u av[4];
#pragma unroll
    for (int j = 0; j < 4; ++j) {
        const int b = j * 256 + tid;
        av[j] = *(const v4u*)(addr + (size_t)b * Nc + n0);
    }
#pragma unroll
    for (int j = 0; j < 4; ++j) {
        const int b = j * 256 + tid;
        const uint32_t aw[4] = {av[j].x, av[j].y, av[j].z, av[j].w};
        int res[8];
#pragma unroll
        for (int p = 0; p < 8; ++p) {
            const uint32_t a = (aw[p >> 1] >> ((p & 1) * 16)) & 0xffffu;
            res[p] = (int)((prow[p * 2048 + (a >> 5)] >> (a & 31)) & 1u);
        }
        v4i* op = (v4i*)(out + (size_t)b * Nc + n0);
        v4i r0 = {res[0], res[1], res[2], res[3]};
        v4i r1 = {res[4], res[5], res[6], res[7]};
        __builtin_nontemporal_store(r0, op);
        __builtin_nontemporal_store(r1, op + 1);
    }
}

// ---------------------------------------------------------------------------
// Fallback (original verified kernel) in case ws is too small.
// ---------------------------------------------------------------------------
__global__ __launch_bounds__(256) void ram_lookup_fused(
    const int* __restrict__ input_bits,
    const int* __restrict__ connections,
    const int* __restrict__ memory,
    int* __restrict__ out)
{
    __shared__ uint32_t bits[Tc / 32];

    const int b    = blockIdx.x;
    const int tid  = threadIdx.x;
    const int lane = tid & 63;
    const int wave = tid >> 6;

    const int* row = input_bits + (size_t)b * Tc;

#pragma unroll
    for (int i = 0; i < Tc / 256; ++i) {
        const int pos = i * 256 + wave * 64 + lane;
        const unsigned long long m = __ballot(row[pos] & 1);
        if (lane == 0) {
            const int w64 = i * 4 + wave;
            bits[w64 * 2]     = (uint32_t)m;
            bits[w64 * 2 + 1] = (uint32_t)(m >> 32);
        }
    }
    __syncthreads();

    int vals[Nc / 256];
#pragma unroll
    for (int i = 0; i < Nc / 256; ++i) {
        const int n = i * 256 + tid;
        const int4* cp = (const int4*)(connections + n * Kc);
        const int4 c0 = cp[0], c1 = cp[1], c2 = cp[2], c3 = cp[3];
        const int c[16] = {c0.x, c0.y, c0.z, c0.w,
                           c1.x, c1.y, c1.z, c1.w,
                           c2.x, c2.y, c2.z, c2.w,
                           c3.x, c3.y, c3.z, c3.w};
        uint32_t a = 0;
#pragma unroll
        for (int k = 0; k < 16; ++k) {
            const uint32_t t = (uint32_t)c[k];
            a |= ((bits[t >> 5] >> (t & 31)) & 1u) << k;
        }
        vals[i] = __builtin_nontemporal_load(memory + ((size_t)n << 16) + a);
    }

#pragma unroll
    for (int i = 0; i < Nc / 256; ++i) {
        __builtin_nontemporal_store(vals[i] & 1,
                                    out + (size_t)b * Nc + i * 256 + tid);
    }
}

extern "C" void kernel_launch(void* const* d_in, const int* in_sizes, int n_in,
                              void* d_out, int out_size, void* d_ws, size_t ws_size,
                              hipStream_t stream) {
    const int* input_bits  = (const int*)d_in[0];  // B*T
    const int* connections = (const int*)d_in[1];  // N*K
    const int* memory      = (const int*)d_in[2];  // N*M
    int* out               = (int*)d_out;          // B*N (bool -> int32)

    const size_t addr_bytes   = (size_t)Bc * Nc * sizeof(unsigned short); // 4 MB
    const size_t packed_bytes = (size_t)Nc * Mc / 8;                      // 16 MB

    if (ws_size >= addr_bytes + packed_bytes) {
        unsigned short* addr     = (unsigned short*)d_ws;
        unsigned long long* pk64 = (unsigned long long*)((char*)d_ws + addr_bytes);

        hipLaunchKernelGGL(pack_bit0, dim3(PACK_GRID), dim3(PACK_BLK), 0, stream,
                           memory, pk64);
        hipLaunchKernelGGL(addr_kernel, dim3(Bc), dim3(256), 0, stream,
                           input_bits, connections, addr);
        hipLaunchKernelGGL(probe_kernel, dim3(GRID_B), dim3(256), 0, stream,
                           (const uint32_t*)pk64, addr, out);
    } else {
        hipLaunchKernelGGL(ram_lookup_fused, dim3(Bc), dim3(256), 0, stream,
                           input_bits, connections, memory, out);
    }
}

// Round 7
// 740.836 us; speedup vs baseline: 1.0074x; 1.0074x over previous
//
#include <hip/hip_runtime.h>
#include <cstdint>

// Problem constants (fixed by reference):
#define Bc 1024
#define Tc 4096
#define Nc 2048
#define Kc 16
#define Mc 65536

#define PACK_GRID 2048
#define PACK_BLK  256

// ---------------------------------------------------------------------------
// Kernel P: pack bit0 of memory[N][M] into a 16 MB bitset in workspace.
// VERBATIM round-1 verified structure with ONE change: plain loads instead of
// __builtin_nontemporal_load. Cross-round decomposition (R0/R1/R4/R5/R6)
// shows every NT-load kernel reading `memory` capped at ~1.5 TB/s regardless
// of pattern, while all plain-load kernels ran at expected speed.
// Layout: packed64[e >> 6] bit (e & 63) = bit0 of element e, e = n*Mc + m.
// ---------------------------------------------------------------------------
__global__ __launch_bounds__(PACK_BLK) void pack_bit0(
    const int* __restrict__ memory,
    unsigned long long* __restrict__ packed)   // Nc*Mc/64 u64 = 16 MB
{
    const int tid  = threadIdx.x;
    const int lane = tid & 63;
    const size_t stride = (size_t)PACK_GRID * PACK_BLK;   // 524288
    size_t base = (size_t)blockIdx.x * PACK_BLK + tid;

    for (int it = 0; it < 256 / 8; ++it) {                // 32 outer iters
        int v[8];
#pragma unroll
        for (int j = 0; j < 8; ++j)                        // 8 loads in flight
            v[j] = memory[base + (size_t)j * stride];      // PLAIN load
#pragma unroll
        for (int j = 0; j < 8; ++j) {
            const unsigned long long m = __ballot(v[j] & 1);
            if (lane == 0) {
                // lane0's elem index is 64-aligned (blockDim=256, stride%64==0)
                packed[(base + (size_t)j * stride) >> 6] = m;
            }
        }
        base += 8 * stride;
    }
}

// ---------------------------------------------------------------------------
// Kernel L: b-major lookup against the packed table (VERBATIM round-1
// verified kernel — all plain loads; the 16 MB table is L2/L3-resident).
// ---------------------------------------------------------------------------
__global__ __launch_bounds__(256) void ram_lookup_packed(
    const int* __restrict__ input_bits,       // (B, T) int32 in {0,1}
    const int* __restrict__ connections,      // (N, K) int32 in [0, T)
    const uint32_t* __restrict__ packed,      // Nc * (Mc/32) u32
    int* __restrict__ out)                    // (B, N) bool-as-int32
{
    __shared__ uint32_t bits[Tc / 32];        // 128 words = 512 B

    const int b    = blockIdx.x;
    const int tid  = threadIdx.x;
    const int lane = tid & 63;
    const int wave = tid >> 6;

    const int* row = input_bits + (size_t)b * Tc;

    // ---- Phase 1: build input bitset via ballot ----
#pragma unroll
    for (int i = 0; i < Tc / 256; ++i) {      // 16 iterations
        const int pos = i * 256 + wave * 64 + lane;
        const unsigned long long m = __ballot(row[pos] & 1);
        if (lane == 0) {
            const int w64 = i * 4 + wave;
            bits[w64 * 2]     = (uint32_t)m;
            bits[w64 * 2 + 1] = (uint32_t)(m >> 32);
        }
    }
    __syncthreads();

    // ---- Phase 2+3 fused: addr -> immediate packed-table probe ----
    int vals[Nc / 256];
#pragma unroll
    for (int i = 0; i < Nc / 256; ++i) {      // 8 independent probe chains
        const int n = i * 256 + tid;
        const int4* cp = (const int4*)(connections + n * Kc);
        const int4 c0 = cp[0], c1 = cp[1], c2 = cp[2], c3 = cp[3];
        const int c[16] = {c0.x, c0.y, c0.z, c0.w,
                           c1.x, c1.y, c1.z, c1.w,
                           c2.x, c2.y, c2.z, c2.w,
                           c3.x, c3.y, c3.z, c3.w};
        uint32_t a = 0;
#pragma unroll
        for (int k = 0; k < 16; ++k) {
            const uint32_t t = (uint32_t)c[k];
            a |= ((bits[t >> 5] >> (t & 31)) & 1u) << k;
        }
        const uint32_t w = packed[((uint32_t)n << 11) + (a >> 5)];
        vals[i] = (int)((w >> (a & 31)) & 1u);
    }

    // ---- Phase 4: coalesced stores ----
#pragma unroll
    for (int i = 0; i < Nc / 256; ++i) {
        out[(size_t)b * Nc + i * 256 + tid] = vals[i];
    }
}

// ---------------------------------------------------------------------------
// Fallback (original verified kernel, NT removed) in case ws is too small.
// ---------------------------------------------------------------------------
__global__ __launch_bounds__(256) void ram_lookup_fused(
    const int* __restrict__ input_bits,
    const int* __restrict__ connections,
    const int* __restrict__ memory,
    int* __restrict__ out)
{
    __shared__ uint32_t bits[Tc / 32];

    const int b    = blockIdx.x;
    const int tid  = threadIdx.x;
    const int lane = tid & 63;
    const int wave = tid >> 6;

    const int* row = input_bits + (size_t)b * Tc;

#pragma unroll
    for (int i = 0; i < Tc / 256; ++i) {
        const int pos = i * 256 + wave * 64 + lane;
        const unsigned long long m = __ballot(row[pos] & 1);
        if (lane == 0) {
            const int w64 = i * 4 + wave;
            bits[w64 * 2]     = (uint32_t)m;
            bits[w64 * 2 + 1] = (uint32_t)(m >> 32);
        }
    }
    __syncthreads();

    int vals[Nc / 256];
#pragma unroll
    for (int i = 0; i < Nc / 256; ++i) {
        const int n = i * 256 + tid;
        const int4* cp = (const int4*)(connections + n * Kc);
        const int4 c0 = cp[0], c1 = cp[1], c2 = cp[2], c3 = cp[3];
        const int c[16] = {c0.x, c0.y, c0.z, c0.w,
                           c1.x, c1.y, c1.z, c1.w,
                           c2.x, c2.y, c2.z, c2.w,
                           c3.x, c3.y, c3.z, c3.w};
        uint32_t a = 0;
#pragma unroll
        for (int k = 0; k < 16; ++k) {
            const uint32_t t = (uint32_t)c[k];
            a |= ((bits[t >> 5] >> (t & 31)) & 1u) << k;
        }
        vals[i] = memory[((size_t)n << 16) + a];
    }

#pragma unroll
    for (int i = 0; i < Nc / 256; ++i) {
        out[(size_t)b * Nc + i * 256 + tid] = vals[i] & 1;
    }
}

extern "C" void kernel_launch(void* const* d_in, const int* in_sizes, int n_in,
                              void* d_out, int out_size, void* d_ws, size_t ws_size,
                              hipStream_t stream) {
    const int* input_bits  = (const int*)d_in[0];  // B*T
    const int* connections = (const int*)d_in[1];  // N*K
    const int* memory      = (const int*)d_in[2];  // N*M
    int* out               = (int*)d_out;          // B*N (bool -> int32)

    const size_t packed_bytes = (size_t)Nc * Mc / 8;   // 16 MB

    if (ws_size >= packed_bytes) {
        unsigned long long* pk64 = (unsigned long long*)d_ws;
        hipLaunchKernelGGL(pack_bit0, dim3(PACK_GRID), dim3(PACK_BLK), 0, stream,
                           memory, pk64);
        hipLaunchKernelGGL(ram_lookup_packed, dim3(Bc), dim3(256), 0, stream,
                           input_bits, connections, (const uint32_t*)pk64, out);
    } else {
        hipLaunchKernelGGL(ram_lookup_fused, dim3(Bc), dim3(256), 0, stream,
                           input_bits, connections, memory, out);
    }
}

// Round 8
// 738.199 us; speedup vs baseline: 1.0110x; 1.0036x over previous
//
#include <hip/hip_runtime.h>
#include <cstdint>

// Problem constants (fixed by reference):
#define Bc 1024
#define Tc 4096
#define Nc 2048
#define Kc 16
#define Mc 65536

#define SCAN_GRID 2048
#define SCAN_BLK  256

// clang ext_vector type (HIP_vector_type int4 not accepted by some builtins;
// also gives clean dwordx4 codegen).
typedef int v4i __attribute__((ext_vector_type(4)));

// ---------------------------------------------------------------------------
// Kernel P: pack bit0 of memory[N][M] into a 16 MB bitset in workspace.
// Grid-strided like the R1/R7 pack (globally quasi-sequential sweep) but with
// dwordx4 loads (1 KB/wave-instr instead of 256 B) — the one untested
// variable in the "512 MB scan caps at 1.5 TB/s" mystery. 8 loads in flight
// per thread; 2048 blocks x 256 thr = 32 waves/CU.
//
// Packing layout (R4-verified algebra): chunk q = 256 consecutive elements
// (one wave-load). Lane l holds elements q*256 + 4l + c (c = component).
// word = q*8 + c*2 + (l>>5), bit = l&31.
// ---------------------------------------------------------------------------
__global__ __launch_bounds__(SCAN_BLK) void pack_bit0_v4(
    const int* __restrict__ memory,
    uint32_t* __restrict__ packed)          // Nc*2048 u32 = 16 MB
{
    const int tid  = threadIdx.x;
    const int lane = tid & 63;
    const size_t g      = (size_t)blockIdx.x * SCAN_BLK + tid;  // v4i index
    const size_t stride = (size_t)SCAN_GRID * SCAN_BLK;         // 524288 v4i
    const v4i* src = (const v4i*)memory;

    // total v4i = Nc*Mc/4 = 32M = 64 * stride
    for (int it = 0; it < 8; ++it) {
        v4i v[8];
        size_t idx[8];
#pragma unroll
        for (int j = 0; j < 8; ++j) {       // 8 x dwordx4 in flight
            idx[j] = (size_t)(it * 8 + j) * stride + g;
            v[j] = src[idx[j]];
        }
#pragma unroll
        for (int j = 0; j < 8; ++j) {
            const unsigned long long m0 = __ballot(v[j].x & 1);
            const unsigned long long m1 = __ballot(v[j].y & 1);
            const unsigned long long m2 = __ballot(v[j].z & 1);
            const unsigned long long m3 = __ballot(v[j].w & 1);
            if (lane < 8) {
                const int c = lane >> 1;
                const unsigned long long mm =
                    (c == 0) ? m0 : (c == 1) ? m1 : (c == 2) ? m2 : m3;
                // wave-base v4i index is 64-aligned -> chunk id
                const size_t q = (idx[j] - lane) >> 6;
                packed[q * 8 + lane] = (uint32_t)(mm >> ((lane & 1) << 5));
            }
        }
    }
}

// ---------------------------------------------------------------------------
// Kernel L: b-major fused lookup against the packed table (R1-verified shell;
// probe index formula is the R4-verified algebra for the layout above):
//   word = (n<<11) + ((a>>8)<<3) + ((a&3)<<1) + ((a>>7)&1), bit = (a>>2)&31.
// ---------------------------------------------------------------------------
__global__ __launch_bounds__(256) void ram_lookup_packed(
    const int* __restrict__ input_bits,       // (B, T) int32 in {0,1}
    const int* __restrict__ connections,      // (N, K) int32 in [0, T)
    const uint32_t* __restrict__ packed,      // Nc * 2048 u32
    int* __restrict__ out)                    // (B, N) bool-as-int32
{
    __shared__ uint32_t bits[Tc / 32];        // 128 words = 512 B

    const int b    = blockIdx.x;
    const int tid  = threadIdx.x;
    const int lane = tid & 63;
    const int wave = tid >> 6;

    const int* row = input_bits + (size_t)b * Tc;

    // ---- Phase 1: build input bitset via ballot ----
#pragma unroll
    for (int i = 0; i < Tc / 256; ++i) {      // 16 iterations
        const int pos = i * 256 + wave * 64 + lane;
        const unsigned long long m = __ballot(row[pos] & 1);
        if (lane == 0) {
            const int w64 = i * 4 + wave;
            bits[w64 * 2]     = (uint32_t)m;
            bits[w64 * 2 + 1] = (uint32_t)(m >> 32);
        }
    }
    __syncthreads();

    // ---- Phase 2+3 fused: addr -> immediate packed-table probe ----
    int vals[Nc / 256];
#pragma unroll
    for (int i = 0; i < Nc / 256; ++i) {      // 8 independent probe chains
        const int n = i * 256 + tid;
        const int4* cp = (const int4*)(connections + n * Kc);
        const int4 c0 = cp[0], c1 = cp[1], c2 = cp[2], c3 = cp[3];
        const int c[16] = {c0.x, c0.y, c0.z, c0.w,
                           c1.x, c1.y, c1.z, c1.w,
                           c2.x, c2.y, c2.z, c2.w,
                           c3.x, c3.y, c3.z, c3.w};
        uint32_t a = 0;
#pragma unroll
        for (int k = 0; k < 16; ++k) {
            const uint32_t t = (uint32_t)c[k];
            a |= ((bits[t >> 5] >> (t & 31)) & 1u) << k;
        }
        const uint32_t widx = ((uint32_t)n << 11)
                            + ((a >> 8) << 3) + ((a & 3) << 1) + ((a >> 7) & 1);
        vals[i] = (int)((packed[widx] >> ((a >> 2) & 31)) & 1u);
    }

    // ---- Phase 4: coalesced stores ----
#pragma unroll
    for (int i = 0; i < Nc / 256; ++i) {
        out[(size_t)b * Nc + i * 256 + tid] = vals[i];
    }
}

// ---------------------------------------------------------------------------
// Fallback (original verified kernel) in case ws is too small.
// ---------------------------------------------------------------------------
__global__ __launch_bounds__(256) void ram_lookup_fused(
    const int* __restrict__ input_bits,
    const int* __restrict__ connections,
    const int* __restrict__ memory,
    int* __restrict__ out)
{
    __shared__ uint32_t bits[Tc / 32];

    const int b    = blockIdx.x;
    const int tid  = threadIdx.x;
    const int lane = tid & 63;
    const int wave = tid >> 6;

    const int* row = input_bits + (size_t)b * Tc;

#pragma unroll
    for (int i = 0; i < Tc / 256; ++i) {
        const int pos = i * 256 + wave * 64 + lane;
        const unsigned long long m = __ballot(row[pos] & 1);
        if (lane == 0) {
            const int w64 = i * 4 + wave;
            bits[w64 * 2]     = (uint32_t)m;
            bits[w64 * 2 + 1] = (uint32_t)(m >> 32);
        }
    }
    __syncthreads();

    int vals[Nc / 256];
#pragma unroll
    for (int i = 0; i < Nc / 256; ++i) {
        const int n = i * 256 + tid;
        const int4* cp = (const int4*)(connections + n * Kc);
        const int4 c0 = cp[0], c1 = cp[1], c2 = cp[2], c3 = cp[3];
        const int c[16] = {c0.x, c0.y, c0.z, c0.w,
                           c1.x, c1.y, c1.z, c1.w,
                           c2.x, c2.y, c2.z, c2.w,
                           c3.x, c3.y, c3.z, c3.w};
        uint32_t a = 0;
#pragma unroll
        for (int k = 0; k < 16; ++k) {
            const uint32_t t = (uint32_t)c[k];
            a |= ((bits[t >> 5] >> (t & 31)) & 1u) << k;
        }
        vals[i] = memory[((size_t)n << 16) + a];
    }

#pragma unroll
    for (int i = 0; i < Nc / 256; ++i) {
        out[(size_t)b * Nc + i * 256 + tid] = vals[i] & 1;
    }
}

extern "C" void kernel_launch(void* const* d_in, const int* in_sizes, int n_in,
                              void* d_out, int out_size, void* d_ws, size_t ws_size,
                              hipStream_t stream) {
    const int* input_bits  = (const int*)d_in[0];  // B*T
    const int* connections = (const int*)d_in[1];  // N*K
    const int* memory      = (const int*)d_in[2];  // N*M
    int* out               = (int*)d_out;          // B*N (bool -> int32)

    const size_t packed_bytes = (size_t)Nc * Mc / 8;   // 16 MB

    if (ws_size >= packed_bytes) {
        uint32_t* packed = (uint32_t*)d_ws;
        hipLaunchKernelGGL(pack_bit0_v4, dim3(SCAN_GRID), dim3(SCAN_BLK), 0, stream,
                           memory, packed);
        hipLaunchKernelGGL(ram_lookup_packed, dim3(Bc), dim3(256), 0, stream,
                           input_bits, connections, packed, out);
    } else {
        hipLaunchKernelGGL(ram_lookup_fused, dim3(Bc), dim3(256), 0, stream,
                           input_bits, connections, memory, out);
    }
}